// Round 4
// baseline (1062.240 us; speedup 1.0000x reference)
//
#include <hip/hip_runtime.h>
#include <stdint.h>

#define B_ 8
#define L_ 4096
#define DM_ 1024
#define H_ 16
#define DH_ 64
#define U_ 45
#define BH_ 128
#define CHUNKS_ 4

typedef unsigned short u16;
typedef unsigned int u32;
typedef __attribute__((ext_vector_type(8))) short short8;
typedef __attribute__((ext_vector_type(4))) float f32x4;

__device__ __forceinline__ u16 f2bf_rne(float x){
  u32 u = __float_as_uint(x);
  return (u16)((u + 0x7FFFu + ((u >> 16) & 1u)) >> 16);
}
__device__ __forceinline__ float bf2f(u16 v){ return __uint_as_float(((u32)v) << 16); }

// async global->LDS, 16B per lane, LDS dest = wave-uniform base + lane*16
__device__ __forceinline__ void gload_lds16(const void* g, void* l){
  auto gp = (const __attribute__((address_space(1))) u32*)(uintptr_t)g;
  auto lp = (__attribute__((address_space(3))) u32*)(u32)(uintptr_t)l;
  __builtin_amdgcn_global_load_lds(gp, lp, 16, 0, 0);
}

__device__ __forceinline__ void split1(float x, u16& h, u16& l){
  h = f2bf_rne(x);
  l = f2bf_rne(x - bf2f(h));
}

// ---------------- weight prep ----------------
__global__ void prep_w(const float* __restrict__ Wq, const float* __restrict__ Wk,
                       const float* __restrict__ Wv,
                       u16* __restrict__ WQH, u16* __restrict__ WQL,
                       u16* __restrict__ WKH, u16* __restrict__ WKL,
                       u16* __restrict__ WVH){
  const int i = (blockIdx.x * 256 + threadIdx.x) * 4;
  float4 a; ushort4 h, l;
  a = *(const float4*)(Wq + i);
  split1(a.x, h.x, l.x); split1(a.y, h.y, l.y); split1(a.z, h.z, l.z); split1(a.w, h.w, l.w);
  *(ushort4*)(WQH + i) = h; *(ushort4*)(WQL + i) = l;
  a = *(const float4*)(Wk + i);
  split1(a.x, h.x, l.x); split1(a.y, h.y, l.y); split1(a.z, h.z, l.z); split1(a.w, h.w, l.w);
  *(ushort4*)(WKH + i) = h; *(ushort4*)(WKL + i) = l;
  a = *(const float4*)(Wv + i);
  split1(a.x, h.x, l.x); split1(a.y, h.y, l.y); split1(a.z, h.z, l.z); split1(a.w, h.w, l.w);
  *(ushort4*)(WVH + i) = h;
}

// ---------------- Q -> hi/lo bf16 split ----------------
__global__ void splitq(const float* __restrict__ Q, u16* __restrict__ QH,
                       u16* __restrict__ QL){
  const int i = (blockIdx.x * 256 + threadIdx.x) * 4;
  const float4 a = *(const float4*)(Q + i);
  ushort4 h, l;
  split1(a.x, h.x, l.x); split1(a.y, h.y, l.y); split1(a.z, h.z, l.z); split1(a.w, h.w, l.w);
  *(ushort4*)(QH + i) = h; *(ushort4*)(QL + i) = l;
}

// ---------------- gather sampled K rows -> hi/lo bf16, padded to 48 rows ----------------
__global__ void gather_rows(const float* __restrict__ K, const int* __restrict__ IDX,
                            u16* __restrict__ GATHH, u16* __restrict__ GATHL){
  const int blk = blockIdx.x;           // B_*48
  const int b = blk / 48, u = blk % 48;
  const int t = threadIdx.x;
  float4 v = make_float4(0.f, 0.f, 0.f, 0.f);
  if (u < U_){
    const int row = IDX[u];
    v = ((const float4*)(K + ((size_t)b * L_ + row) * DM_))[t];
  }
  ushort4 h, l;
  split1(v.x, h.x, l.x); split1(v.y, h.y, l.y); split1(v.z, h.z, l.z); split1(v.w, h.w, l.w);
  ((ushort4*)(GATHH + ((size_t)(b * 48 + u)) * DM_))[t] = h;
  ((ushort4*)(GATHL + ((size_t)(b * 48 + u)) * DM_))[t] = l;
}

// ---------------- 3-pass GEMM with pre-split bf16 A (no split VALU) ----------------
// C[g,c] = sum_k A[g,k]*W[c,k] + bias[c], accuracy ~2^-16.
// All tiles 128B-row bf16, XOR swizzle c^(row&7).
// OUTMODE 2: fp32 [Mx1024]; OUTMODE 4: no output (WITHM only).
// WITHM: fuse M = max-mean(q . k_samp) -> MBUF.
template<int OUTMODE, bool WITHM>
__launch_bounds__(256, 2)
__global__ void gemm_asplit(const u16* __restrict__ AH, const u16* __restrict__ AL,
                            const u16* __restrict__ BHp, const u16* __restrict__ BLp,
                            const float* __restrict__ bias, void* __restrict__ outp,
                            const u16* __restrict__ KSH, const u16* __restrict__ KSL,
                            float* __restrict__ MBUF){
  constexpr int LDSB = WITHM ? 69632 : 65536;
  __shared__ __attribute__((aligned(16))) char smem[LDSB];
  u16* Ahs = (u16*)smem;                    // 16 KB each
  u16* Als = (u16*)(smem + 16384);
  u16* Bhs = (u16*)(smem + 32768);
  u16* Bls = (u16*)(smem + 49152);

  const int n0 = blockIdx.x * 128;
  const int m0 = blockIdx.y * 128;
  const int t = threadIdx.x;
  const int w = t >> 6, lane = t & 63;
  const int wr = w >> 1, wc = w & 1;
  const int m16 = lane & 15, q4 = lane >> 4;

  f32x4 acc[4][4];
#pragma unroll
  for (int i = 0; i < 4; i++)
#pragma unroll
    for (int j = 0; j < 4; j++) acc[i][j] = (f32x4){0.f, 0.f, 0.f, 0.f};

  const int brow = lane >> 3;            // 8 rows per staging instr
  const int bcN  = lane & 7;             // chunk slot

  for (int kt = 0; kt < 16; kt++){
    const int k0 = kt * 64;
#pragma unroll
    for (int ii = 0; ii < 4; ii++){
      const int nn = w * 4 + ii;
      const int rb = 8 * nn + brow;
      const int cb = bcN ^ (brow & 7);
      const size_t goA = (size_t)(m0 + rb) * DM_ + (k0 + cb * 8);
      const size_t goB = (size_t)(n0 + rb) * DM_ + (k0 + cb * 8);
      gload_lds16(AH + goA, Ahs + nn * 512);
      gload_lds16(AL + goA, Als + nn * 512);
      gload_lds16(BHp + goB, Bhs + nn * 512);
      gload_lds16(BLp + goB, Bls + nn * 512);
    }
    __syncthreads();

#pragma unroll
    for (int ks = 0; ks < 2; ks++){
      const int gcb = ks * 4 + q4;
      const int posm = (gcb ^ (m16 & 7)) * 8;
      short8 ah[4], al[4], bh8[4], bl8[4];
#pragma unroll
      for (int i = 0; i < 4; i++){
        const int rowa = (wr * 64 + i * 16 + m16) * 64;
        ah[i] = *(const short8*)(Ahs + rowa + posm);
        al[i] = *(const short8*)(Als + rowa + posm);
      }
#pragma unroll
      for (int j = 0; j < 4; j++){
        const int rowb = (wc * 64 + j * 16 + m16) * 64;
        bh8[j] = *(const short8*)(Bhs + rowb + posm);
        bl8[j] = *(const short8*)(Bls + rowb + posm);
      }
#pragma unroll
      for (int i = 0; i < 4; i++)
#pragma unroll
        for (int j = 0; j < 4; j++){
          acc[i][j] = __builtin_amdgcn_mfma_f32_16x16x32_bf16(ah[i], bh8[j], acc[i][j], 0, 0, 0);
          acc[i][j] = __builtin_amdgcn_mfma_f32_16x16x32_bf16(ah[i], bl8[j], acc[i][j], 0, 0, 0);
          acc[i][j] = __builtin_amdgcn_mfma_f32_16x16x32_bf16(al[i], bh8[j], acc[i][j], 0, 0, 0);
        }
    }
    __syncthreads();
  }

  // C/D layout: col=lane&15, row=(lane>>4)*4+reg  [verified m89/m91]
  if constexpr (OUTMODE == 2){
#pragma unroll
    for (int j = 0; j < 4; j++){
      const int c = n0 + wc * 64 + j * 16 + m16;
      const float bv = bias[c];
#pragma unroll
      for (int i = 0; i < 4; i++){
        const int mb = m0 + wr * 64 + i * 16 + q4 * 4;
#pragma unroll
        for (int r = 0; r < 4; r++)
          ((float*)outp)[(size_t)(mb + r) * DM_ + c] = acc[i][j][r] + bv;
      }
    }
  }

  if constexpr (WITHM){
    float* mt = (float*)smem + w * (64 * 68);   // per-wave 64x68 fp32
#pragma unroll
    for (int j = 0; j < 4; j++){
      const float bv = bias[n0 + wc * 64 + j * 16 + m16];
#pragma unroll
      for (int i = 0; i < 4; i++)
#pragma unroll
        for (int r = 0; r < 4; r++)
          mt[(i * 16 + q4 * 4 + r) * 68 + (j * 16 + m16)] = acc[i][j][r] + bv;
    }
    // per-wave: qk = (64 q rows) x (48 k_samp rows), 3-pass, M=max-mean
    const int bb = m0 >> 12;
    const int head = (n0 >> 6) + wc;
    const int bh2 = bb * H_ + head;
    f32x4 S[4][3];
#pragma unroll
    for (int im = 0; im < 4; im++)
#pragma unroll
      for (int jt = 0; jt < 3; jt++) S[im][jt] = (f32x4){0.f, 0.f, 0.f, 0.f};
#pragma unroll
    for (int ks = 0; ks < 2; ks++){
      short8 kh3[3], kl3[3];
#pragma unroll
      for (int jt = 0; jt < 3; jt++){
        const size_t ko = ((size_t)bh2 * 48 + jt * 16 + m16) * 64 + ks * 32 + q4 * 8;
        kh3[jt] = *(const short8*)(KSH + ko);
        kl3[jt] = *(const short8*)(KSL + ko);
      }
#pragma unroll
      for (int im = 0; im < 4; im++){
        const float* ap = mt + (im * 16 + m16) * 68 + ks * 32 + q4 * 8;
        const f32x4 xlo = *(const f32x4*)ap;
        const f32x4 xhi = *(const f32x4*)(ap + 4);
        float xx[8] = {xlo[0], xlo[1], xlo[2], xlo[3], xhi[0], xhi[1], xhi[2], xhi[3]};
        short8 qh, ql;
#pragma unroll
        for (int c = 0; c < 8; c++){
          const u32 ub = __float_as_uint(xx[c]);
          qh[c] = (short)(ub >> 16);
          const float r = xx[c] - __uint_as_float(ub & 0xFFFF0000u);
          ql[c] = (short)(__float_as_uint(r) >> 16);
        }
#pragma unroll
        for (int jt = 0; jt < 3; jt++){
          S[im][jt] = __builtin_amdgcn_mfma_f32_16x16x32_bf16(qh, kh3[jt], S[im][jt], 0, 0, 0);
          S[im][jt] = __builtin_amdgcn_mfma_f32_16x16x32_bf16(qh, kl3[jt], S[im][jt], 0, 0, 0);
          S[im][jt] = __builtin_amdgcn_mfma_f32_16x16x32_bf16(ql, kh3[jt], S[im][jt], 0, 0, 0);
        }
      }
    }
#pragma unroll
    for (int im = 0; im < 4; im++)
#pragma unroll
      for (int r = 0; r < 4; r++){
        float mx = -1e30f, sm = 0.f;
#pragma unroll
        for (int jt = 0; jt < 3; jt++){
          const bool ok = (jt < 2) || (m16 < 13);   // u = jt*16+m16 < 45
          const float v = S[im][jt][r];
          if (ok){ mx = fmaxf(mx, v); sm += v; }
        }
#pragma unroll
        for (int off = 1; off < 16; off <<= 1){
          mx = fmaxf(mx, __shfl_xor(mx, off));
          sm += __shfl_xor(sm, off);
        }
        if (m16 == 0){
          const int l2 = (m0 & 4095) + wr * 64 + im * 16 + q4 * 4 + r;
          MBUF[(size_t)bh2 * L_ + l2] = mx - sm * (1.0f / 45.0f);
        }
      }
  }
}

// ---------------- single-pass GEMM, fp32 A (K/V projections) ----------------
// OUTMODE 1: bf16 scatter [B,H,L,64]; 3: bf16 transposed [B,H,64,L].
template<int OUTMODE>
__launch_bounds__(256, 2)
__global__ void gemm_f32a(const float* __restrict__ A, const u16* __restrict__ BHp,
                          const float* __restrict__ bias, void* __restrict__ outp){
  __shared__ __attribute__((aligned(16))) char smem[49152];
  float* As = (float*)smem;                 // 32 KB
  u16* Bhs = (u16*)(smem + 32768);          // 16 KB

  const int n0 = blockIdx.x * 128;
  const int m0 = blockIdx.y * 128;
  const int t = threadIdx.x;
  const int w = t >> 6, lane = t & 63;
  const int wr = w >> 1, wc = w & 1;
  const int m16 = lane & 15, q4 = lane >> 4;

  f32x4 acc[4][4];
#pragma unroll
  for (int i = 0; i < 4; i++)
#pragma unroll
    for (int j = 0; j < 4; j++) acc[i][j] = (f32x4){0.f, 0.f, 0.f, 0.f};

  const int arow = lane >> 4;
  const int acN  = lane & 15;
  const int brow = lane >> 3;
  const int bcN  = lane & 7;

  for (int kt = 0; kt < 16; kt++){
    const int k0 = kt * 64;
#pragma unroll
    for (int ii = 0; ii < 8; ii++){
      const int nn = w * 8 + ii;
      const int rl = 4 * nn + arow;
      const int c2 = acN ^ (rl & 15);
      gload_lds16(A + (size_t)(m0 + rl) * DM_ + (k0 + c2 * 4), As + nn * 256);
    }
#pragma unroll
    for (int ii = 0; ii < 4; ii++){
      const int nn = w * 4 + ii;
      const int rb = 8 * nn + brow;
      const int cb = bcN ^ (brow & 7);
      gload_lds16(BHp + (size_t)(n0 + rb) * DM_ + (k0 + cb * 8), Bhs + nn * 512);
    }
    __syncthreads();

#pragma unroll
    for (int ks = 0; ks < 2; ks++){
      const int gc0 = ks * 8 + q4 * 2;
      short8 ah[4];
#pragma unroll
      for (int i = 0; i < 4; i++){
        const float* base = As + (wr * 64 + i * 16 + m16) * 64;
        const f32x4 xlo = *(const f32x4*)(base + (gc0 ^ m16) * 4);
        const f32x4 xhi = *(const f32x4*)(base + ((gc0 + 1) ^ m16) * 4);
        float xx[8] = {xlo[0], xlo[1], xlo[2], xlo[3], xhi[0], xhi[1], xhi[2], xhi[3]};
        short8 h;
#pragma unroll
        for (int c = 0; c < 8; c++) h[c] = (short)(__float_as_uint(xx[c]) >> 16);
        ah[i] = h;
      }
      const int gcb = ks * 4 + q4;
      short8 bh8[4];
#pragma unroll
      for (int j = 0; j < 4; j++)
        bh8[j] = *(const short8*)(Bhs + (wc * 64 + j * 16 + m16) * 64 + (gcb ^ (m16 & 7)) * 8);
#pragma unroll
      for (int i = 0; i < 4; i++)
#pragma unroll
        for (int j = 0; j < 4; j++)
          acc[i][j] = __builtin_amdgcn_mfma_f32_16x16x32_bf16(ah[i], bh8[j], acc[i][j], 0, 0, 0);
    }
    __syncthreads();
  }

  if constexpr (OUTMODE == 3){
    u16* tb = (u16*)smem;
    const int b = m0 >> 12;
    const int l0 = m0 & 4095;
#pragma unroll
    for (int p = 0; p < 2; p++){
      if (wc == p){
#pragma unroll
        for (int j = 0; j < 4; j++){
          const int cl = j * 16 + m16;
          const float bv = bias[n0 + p * 64 + cl];
#pragma unroll
          for (int i = 0; i < 4; i++)
#pragma unroll
            for (int r = 0; r < 4; r++){
              const int gl = wr * 64 + i * 16 + q4 * 4 + r;
              tb[cl * 136 + gl] = f2bf_rne(acc[i][j][r] + bv);
            }
        }
      }
      __syncthreads();
      {
        const int cl = t >> 2;
        const int c = n0 + p * 64 + cl;
        const int h = c >> 6, d = c & 63;
        u16* dst = (u16*)outp + ((size_t)((b * H_ + h) * DH_ + d)) * L_ + l0;
#pragma unroll
        for (int k = 0; k < 4; k++){
          const int ch = (t & 3) + k * 4;
          *(short8*)(dst + ch * 8) = *(const short8*)(tb + cl * 136 + ch * 8);
        }
      }
      __syncthreads();
    }
  } else {
#pragma unroll
    for (int j = 0; j < 4; j++){
      const int c = n0 + wc * 64 + j * 16 + m16;
      const float bv = bias[c];
      const int h = c >> 6, d = c & 63;
#pragma unroll
      for (int i = 0; i < 4; i++){
        const int mb = m0 + wr * 64 + i * 16 + q4 * 4;
#pragma unroll
        for (int r = 0; r < 4; r++){
          const int g = mb + r;
          const int b = g >> 12, l2 = g & 4095;
          ((u16*)outp)[(((size_t)(b * H_ + h)) * L_ + l2) * DH_ + d] =
              f2bf_rne(acc[i][j][r] + bv);
        }
      }
    }
  }
}

// ---------------- k_samp hi/lo prep ----------------
__global__ void ksprep(const float* __restrict__ KSAMP, u16* __restrict__ KSH,
                       u16* __restrict__ KSL){
  const int bh = blockIdx.x;
  const int b = bh >> 4, h = bh & 15;
  const int t = threadIdx.x;
  for (int i = t; i < 48 * 64; i += 256){
    const int u = i >> 6, d = i & 63;
    const float v = (u < U_) ? KSAMP[(size_t)(b * 48 + u) * DM_ + h * DH_ + d] : 0.f;
    u16 hh, ll; split1(v, hh, ll);
    KSH[(size_t)bh * 48 * 64 + i] = hh;
    KSL[(size_t)bh * 48 * 64 + i] = ll;
  }
}

// ---------------- iterative top-45 ----------------
__global__ void topk45(const float* __restrict__ MBUF, int* __restrict__ MTOP){
  const int bh = blockIdx.x;
  const int t = threadIdx.x, w = t >> 6, lane = t & 63;
  __shared__ float Mv[L_];
  __shared__ float rv[4];
  __shared__ int ri[4];
  for (int i = t; i < L_; i += 256) Mv[i] = MBUF[(size_t)bh * L_ + i];
  __syncthreads();
  for (int it = 0; it < U_; it++){
    float bv = -1e30f; int bi = 0;
#pragma unroll
    for (int c = 0; c < 16; c++){
      const int idx = c * 256 + t;
      const float v = Mv[idx];
      if (v > bv || (v == bv && idx < bi)){ bv = v; bi = idx; }
    }
#pragma unroll
    for (int off = 1; off < 64; off <<= 1){
      const float ov = __shfl_xor(bv, off);
      const int oi = __shfl_xor(bi, off);
      if (ov > bv || (ov == bv && oi < bi)){ bv = ov; bi = oi; }
    }
    if (lane == 0){ rv[w] = bv; ri[w] = bi; }
    __syncthreads();
    if (t == 0){
      float fb = rv[0]; int fi = ri[0];
#pragma unroll
      for (int s = 1; s < 4; s++)
        if (rv[s] > fb || (rv[s] == fb && ri[s] < fi)){ fb = rv[s]; fi = ri[s]; }
      MTOP[bh * U_ + it] = fi;
      Mv[fi] = -1e30f;
    }
    __syncthreads();
  }
}

// ---------------- recompute selected q rows (3-pass) -> QRED[bh][48][64] ----------------
__global__ void qred_kernel(const u16* __restrict__ QH, const u16* __restrict__ QL,
                            const u16* __restrict__ WQH, const u16* __restrict__ WQL,
                            const float* __restrict__ bq, const int* __restrict__ MTOP,
                            float* __restrict__ QRED){
  const int bh = blockIdx.x;
  const int b = bh >> 4, h = bh & 15;
  const int t = threadIdx.x, w = t >> 6, lane = t & 63;
  const int m16 = lane & 15, q4 = lane >> 4;
  __shared__ int rows[48];
  if (t < 48) rows[t] = (t < U_) ? MTOP[bh * U_ + t] : 0;
  __syncthreads();

  f32x4 acc[3];
#pragma unroll
  for (int i = 0; i < 3; i++) acc[i] = (f32x4){0.f, 0.f, 0.f, 0.f};
  const int c = h * 64 + w * 16 + m16;     // output col for B frag
  const u16* wqh = WQH + (size_t)c * DM_;
  const u16* wql = WQL + (size_t)c * DM_;
  size_t abase[3];
#pragma unroll
  for (int i = 0; i < 3; i++)
    abase[i] = ((size_t)b * L_ + rows[i * 16 + m16]) * DM_;

  for (int kk = 0; kk < 32; kk++){
    const int k = kk * 32 + q4 * 8;
    const short8 bh8 = *(const short8*)(wqh + k);
    const short8 bl8 = *(const short8*)(wql + k);
#pragma unroll
    for (int i = 0; i < 3; i++){
      const short8 ah = *(const short8*)(QH + abase[i] + k);
      const short8 al = *(const short8*)(QL + abase[i] + k);
      acc[i] = __builtin_amdgcn_mfma_f32_16x16x32_bf16(ah, bh8, acc[i], 0, 0, 0);
      acc[i] = __builtin_amdgcn_mfma_f32_16x16x32_bf16(ah, bl8, acc[i], 0, 0, 0);
      acc[i] = __builtin_amdgcn_mfma_f32_16x16x32_bf16(al, bh8, acc[i], 0, 0, 0);
    }
  }
  const float bv = bq[h * 64 + w * 16 + m16];
#pragma unroll
  for (int i = 0; i < 3; i++)
#pragma unroll
    for (int r = 0; r < 4; r++){
      const int row = i * 16 + q4 * 4 + r;
      const float val = (row < U_) ? (acc[i][r] + bv) : 0.f;
      QRED[((size_t)bh * 48 + row) * 64 + (w * 16 + m16)] = val;
    }
}

// ---------------- fused flash-style attention (MFMA) ----------------
__launch_bounds__(256, 2)
__global__ void attn_fused(const float* __restrict__ QRED, const u16* __restrict__ KB,
                           const u16* __restrict__ VT,
                           float* __restrict__ MLP, float* __restrict__ CTXP){
  const int bh = blockIdx.x;
  const int chunk = blockIdx.y;
  const int t = threadIdx.x, w = t >> 6, lane = t & 63;
  const int m16 = lane & 15, q4 = lane >> 4;

  __shared__ __attribute__((aligned(16))) float qs[48 * 68];
  __shared__ __attribute__((aligned(16))) u16 ps[4][48 * 72];

  for (int i = t; i < 48 * 64; i += 256)
    qs[(i >> 6) * 68 + (i & 63)] = QRED[(size_t)bh * 48 * 64 + i] * 0.125f;
  __syncthreads();

  short8 qh[3][2], ql[3][2];
#pragma unroll
  for (int i = 0; i < 3; i++)
#pragma unroll
    for (int ks = 0; ks < 2; ks++){
      const float* ap = qs + (i * 16 + m16) * 68 + ks * 32 + q4 * 8;
      const f32x4 xlo = *(const f32x4*)ap;
      const f32x4 xhi = *(const f32x4*)(ap + 4);
      float xx[8] = {xlo[0], xlo[1], xlo[2], xlo[3], xhi[0], xhi[1], xhi[2], xhi[3]};
      short8 h, l;
#pragma unroll
      for (int c = 0; c < 8; c++){
        const u32 ub = __float_as_uint(xx[c]);
        h[c] = (short)(ub >> 16);
        const float r = xx[c] - __uint_as_float(ub & 0xFFFF0000u);
        l[c] = (short)(__float_as_uint(r) >> 16);
      }
      qh[i][ks] = h; ql[i][ks] = l;
    }

  float m_run[3][4], l_run[3][4];
  f32x4 O[3][4];
#pragma unroll
  for (int i = 0; i < 3; i++)
#pragma unroll
    for (int r = 0; r < 4; r++){
      m_run[i][r] = -1e30f; l_run[i][r] = 0.f;
      O[i][r] = (f32x4){0.f, 0.f, 0.f, 0.f};
    }

  const u16* kb = KB + (size_t)bh * L_ * DH_;
  const u16* vt = VT + (size_t)bh * DH_ * L_;
  const int TPW = L_ / (CHUNKS_ * 4 * 64);
  u16* pw = ps[w];

  for (int tt = 0; tt < TPW; tt++){
    const int t0 = ((chunk * 4 + w) * TPW + tt) * 64;
    f32x4 S[3][4];
#pragma unroll
    for (int i = 0; i < 3; i++)
#pragma unroll
      for (int jt = 0; jt < 4; jt++) S[i][jt] = (f32x4){0.f, 0.f, 0.f, 0.f};
#pragma unroll
    for (int ks = 0; ks < 2; ks++){
      short8 kf[4];
#pragma unroll
      for (int jt = 0; jt < 4; jt++)
        kf[jt] = *(const short8*)(kb + (size_t)(t0 + jt * 16 + m16) * DH_ + ks * 32 + q4 * 8);
#pragma unroll
      for (int i = 0; i < 3; i++)
#pragma unroll
        for (int jt = 0; jt < 4; jt++){
          S[i][jt] = __builtin_amdgcn_mfma_f32_16x16x32_bf16(qh[i][ks], kf[jt], S[i][jt], 0, 0, 0);
          S[i][jt] = __builtin_amdgcn_mfma_f32_16x16x32_bf16(ql[i][ks], kf[jt], S[i][jt], 0, 0, 0);
        }
    }
#pragma unroll
    for (int i = 0; i < 3; i++){
      float mnew[4], alpha[4], psum[4];
#pragma unroll
      for (int r = 0; r < 4; r++){
        float mx = fmaxf(fmaxf(S[i][0][r], S[i][1][r]), fmaxf(S[i][2][r], S[i][3][r]));
        mx = fmaxf(mx, __shfl_xor(mx, 1));
        mx = fmaxf(mx, __shfl_xor(mx, 2));
        mx = fmaxf(mx, __shfl_xor(mx, 4));
        mx = fmaxf(mx, __shfl_xor(mx, 8));
        mnew[r] = fmaxf(m_run[i][r], mx);
        alpha[r] = __expf(m_run[i][r] - mnew[r]);
        m_run[i][r] = mnew[r];
        l_run[i][r] *= alpha[r];
        psum[r] = 0.f;
      }
#pragma unroll
      for (int jo = 0; jo < 4; jo++)
#pragma unroll
        for (int r = 0; r < 4; r++) O[i][jo][r] *= alpha[r];
#pragma unroll
      for (int jt = 0; jt < 4; jt++)
#pragma unroll
        for (int r = 0; r < 4; r++){
          const float pv = __expf(S[i][jt][r] - mnew[r]);
          const u16 pq = f2bf_rne(pv);
          psum[r] += bf2f(pq);
          pw[(i * 16 + q4 * 4 + r) * 72 + jt * 16 + m16] = pq;
        }
#pragma unroll
      for (int r = 0; r < 4; r++){
        float s = psum[r];
        s += __shfl_xor(s, 1); s += __shfl_xor(s, 2);
        s += __shfl_xor(s, 4); s += __shfl_xor(s, 8);
        l_run[i][r] += s;
      }
    }
#pragma unroll
    for (int ks = 0; ks < 2; ks++){
      short8 pa[3], vf[4];
#pragma unroll
      for (int i = 0; i < 3; i++)
        pa[i] = *(const short8*)(pw + (i * 16 + m16) * 72 + ks * 32 + q4 * 8);
#pragma unroll
      for (int jo = 0; jo < 4; jo++)
        vf[jo] = *(const short8*)(vt + (size_t)(jo * 16 + m16) * L_ + t0 + ks * 32 + q4 * 8);
#pragma unroll
      for (int i = 0; i < 3; i++)
#pragma unroll
        for (int jo = 0; jo < 4; jo++)
          O[i][jo] = __builtin_amdgcn_mfma_f32_16x16x32_bf16(pa[i], vf[jo], O[i][jo], 0, 0, 0);
    }
  }

  const int state = (bh * CHUNKS_ + chunk) * 4 + w;
  float* mlp = MLP + (size_t)state * 48 * 2;
  float* ctxp = CTXP + (size_t)state * 48 * 64;
#pragma unroll
  for (int i = 0; i < 3; i++)
#pragma unroll
    for (int r = 0; r < 4; r++){
      const int row = i * 16 + q4 * 4 + r;
      if (m16 == 0){ mlp[row * 2] = m_run[i][r]; mlp[row * 2 + 1] = l_run[i][r]; }
#pragma unroll
      for (int jo = 0; jo < 4; jo++)
        ctxp[row * 64 + jo * 16 + m16] = O[i][jo][r];
    }
}

// ---------------- merge partials + mean over u ----------------
__global__ void attn_combine(const float* __restrict__ MLP, const float* __restrict__ CTXP,
                             float* __restrict__ CTXF){
  const int bh = blockIdx.x;
  const int b = bh >> 4, h = bh & 15;
  const int t = threadIdx.x;
  const int col = t & 63, rg = t >> 6;
  const int NS = CHUNKS_ * 4;              // 16
  __shared__ float ml[CHUNKS_ * 4 * 48 * 2];
  __shared__ float red[4][64];
  for (int i = t; i < NS * 48 * 2; i += 256) ml[i] = MLP[(size_t)bh * NS * 48 * 2 + i];
  __syncthreads();
  float acc = 0.f;
  for (int rr = 0; rr < 12; rr++){
    const int row = rg * 12 + rr;
    if (row >= U_) break;
    float M = -1e30f;
#pragma unroll
    for (int s = 0; s < NS; s++) M = fmaxf(M, ml[s * 96 + row * 2]);
    float num = 0.f, den = 0.f;
#pragma unroll
    for (int s = 0; s < NS; s++){
      const float wgt = __expf(ml[s * 96 + row * 2] - M);
      num += wgt * CTXP[((size_t)bh * NS + s) * 48 * 64 + row * 64 + col];
      den += wgt * ml[s * 96 + row * 2 + 1];
    }
    acc += num / den;
  }
  red[rg][col] = acc;
  __syncthreads();
  if (t < 64){
    const float v = (red[0][t] + red[1][t] + red[2][t] + red[3][t]) * (1.0f / 45.0f);
    CTXF[b * DM_ + t * H_ + h] = v;
  }
}

// ---------------- out[b,j] = ctx_flat[b] . Wo[j,:] + bo[j] ----------------
__global__ void s4_out(const float* __restrict__ CTXF, const float* __restrict__ Wo,
                       const float* __restrict__ bo, float* __restrict__ out){
  const int jb = blockIdx.x;
  const int b = blockIdx.y;
  const int t = threadIdx.x;
  __shared__ float cx[DM_];
  for (int i = t; i < DM_; i += 256) cx[i] = CTXF[b * DM_ + i];
  __syncthreads();
  const int j = jb * 256 + t;
  const float* wrow = Wo + (size_t)j * DM_;
  float acc = bo[j];
  for (int c = 0; c < 256; c++){
    const float4 wv = *(const float4*)(wrow + c * 4);
    const float4 cv = *(const float4*)(cx + c * 4);
    acc += wv.x * cv.x + wv.y * cv.y + wv.z * cv.z + wv.w * cv.w;
  }
  out[b * DM_ + j] = acc;
}

extern "C" void kernel_launch(void* const* d_in, const int* in_sizes, int n_in,
                              void* d_out, int out_size, void* d_ws, size_t ws_size,
                              hipStream_t stream){
  const float* Q  = (const float*)d_in[0];
  const float* K  = (const float*)d_in[1];
  const float* V  = (const float*)d_in[2];
  const float* Wq = (const float*)d_in[3];
  const float* bq = (const float*)d_in[4];
  const float* Wk = (const float*)d_in[5];
  const float* bk = (const float*)d_in[6];
  const float* Wv = (const float*)d_in[7];
  const float* bv = (const float*)d_in[8];
  const float* Wo = (const float*)d_in[9];
  const float* bo = (const float*)d_in[10];
  const int* IDX  = (const int*)d_in[11];
  float* out = (float*)d_out;

  char* p = (char*)d_ws;
  auto alloc = [&](size_t bytes) -> char* {
    char* r = p; p += (bytes + 255) & ~(size_t)255; return r;
  };
  u16*  WQH  = (u16*)alloc((size_t)DM_ * DM_ * 2);
  u16*  WQL  = (u16*)alloc((size_t)DM_ * DM_ * 2);
  u16*  WKH  = (u16*)alloc((size_t)DM_ * DM_ * 2);
  u16*  WKL  = (u16*)alloc((size_t)DM_ * DM_ * 2);
  u16*  WVH  = (u16*)alloc((size_t)DM_ * DM_ * 2);
  u16*  QH   = (u16*)alloc((size_t)B_ * L_ * DM_ * 2);      // 64 MiB
  u16*  QL   = (u16*)alloc((size_t)B_ * L_ * DM_ * 2);      // 64 MiB
  u16*  KB   = (u16*)alloc((size_t)BH_ * L_ * DH_ * 2);     // 64 MiB
  u16*  VT   = (u16*)alloc((size_t)BH_ * DH_ * L_ * 2);     // 64 MiB
  u16*  GATHH= (u16*)alloc((size_t)B_ * 48 * DM_ * 2);
  u16*  GATHL= (u16*)alloc((size_t)B_ * 48 * DM_ * 2);
  float* KSAMP= (float*)alloc((size_t)B_ * 48 * DM_ * 4);
  u16*  KSH  = (u16*)alloc((size_t)BH_ * 48 * DH_ * 2);
  u16*  KSL  = (u16*)alloc((size_t)BH_ * 48 * DH_ * 2);
  float* MBUF = (float*)alloc((size_t)BH_ * L_ * 4);
  int*   MTOP = (int*)alloc((size_t)BH_ * U_ * 4);
  float* QRED = (float*)alloc((size_t)BH_ * 48 * DH_ * 4);
  float* MLP  = (float*)alloc((size_t)BH_ * CHUNKS_ * 4 * 48 * 2 * 4);
  float* CTXP = (float*)alloc((size_t)BH_ * CHUNKS_ * 4 * 48 * 64 * 4);  // 25 MiB
  float* CTXF = (float*)alloc((size_t)B_ * DM_ * 4);

  prep_w<<<dim3(1024), dim3(256), 0, stream>>>(Wq, Wk, Wv, WQH, WQL, WKH, WKL, WVH);
  splitq<<<dim3(B_ * L_ * DM_ / 1024), dim3(256), 0, stream>>>(Q, QH, QL);
  gather_rows<<<dim3(B_ * 48), dim3(256), 0, stream>>>(K, IDX, GATHH, GATHL);
  gemm_asplit<2, false><<<dim3(8, 3), dim3(256), 0, stream>>>(
      GATHH, GATHL, WKH, WKL, bk, (void*)KSAMP, nullptr, nullptr, nullptr);
  ksprep<<<dim3(BH_), dim3(256), 0, stream>>>(KSAMP, KSH, KSL);
  gemm_asplit<4, true><<<dim3(8, 256), dim3(256), 0, stream>>>(
      QH, QL, WQH, WQL, bq, nullptr, KSH, KSL, MBUF);
  gemm_f32a<1><<<dim3(8, 256), dim3(256), 0, stream>>>(K, WKH, bk, (void*)KB);
  gemm_f32a<3><<<dim3(8, 256), dim3(256), 0, stream>>>(V, WVH, bv, (void*)VT);
  topk45<<<dim3(BH_), dim3(256), 0, stream>>>(MBUF, MTOP);
  qred_kernel<<<dim3(BH_), dim3(256), 0, stream>>>(QH, QL, WQH, WQL, bq, MTOP, QRED);
  attn_fused<<<dim3(BH_, CHUNKS_), dim3(256), 0, stream>>>(QRED, KB, VT, MLP, CTXP);
  attn_combine<<<dim3(BH_), dim3(256), 0, stream>>>(MLP, CTXP, CTXF);
  s4_out<<<dim3(4, 8), dim3(256), 0, stream>>>(CTXF, Wo, bo, out);
}